// Round 15
// baseline (148.077 us; speedup 1.0000x reference)
//
#include <hip/hip_runtime.h>
#include <hip/hip_fp16.h>
#include <math.h>

#define RR 128          // spatial resolution (grid_space + features)
#define TT 150          // time resolution
#define NCH 48          // RANK*OUT_DIM*TIME_RANK
#define NF 32           // feature channels

typedef float vf2 __attribute__((ext_vector_type(2)));
typedef unsigned int u4v __attribute__((ext_vector_type(4)));
typedef _Float16 h2 __attribute__((ext_vector_type(2)));
typedef _Float16 h4 __attribute__((ext_vector_type(4)));
typedef float fv4 __attribute__((ext_vector_type(4)));

__device__ __forceinline__ h2 pack2(float a, float b) {
    h2 r; r[0] = (_Float16)a; r[1] = (_Float16)b; return r;
}
// fp8 e4m3 unpack with packed-f32 accumulate (v_pk_fma_f32)
__device__ __forceinline__ void up4p(uint u, vf2 s, vf2* a) {
    a[0] += __builtin_amdgcn_cvt_pk_f32_fp8(u, false) * s;
    a[1] += __builtin_amdgcn_cvt_pk_f32_fp8(u, true) * s;
}
__device__ __forceinline__ void up16p(u4v q, float sf, vf2* a) {
    vf2 s; s[0] = sf; s[1] = sf;
    up4p(q[0], s, a + 0); up4p(q[1], s, a + 2);
    up4p(q[2], s, a + 4); up4p(q[3], s, a + 6);
}

// ---- transpose+cast grid_space [3][48][16384] f32 -> [3][16384][48] fp8 (x128) ----
__global__ __launch_bounds__(256) void tgsp_8(const float* __restrict__ in,
                                              uint* __restrict__ out) { // 4 fp8/word
    __shared__ float lds[48][65];
    const int t = threadIdx.x;
    const int p = blockIdx.x >> 8;          // plane
    const int tile = blockIdx.x & 255;
    const size_t V = (size_t)RR * RR;       // 16384
    const size_t v0 = (size_t)tile * 64;
    const float* ip = in + (size_t)p * NCH * V;
    uint* op = out + (size_t)p * V * 12;    // 12 words per position
    #pragma unroll
    for (int k = 0; k < 12; k++) {
        int idx = k * 256 + t; int c = idx >> 6; int vv = idx & 63;
        lds[c][vv] = ip[(size_t)c * V + v0 + vv];
    }
    __syncthreads();
    #pragma unroll
    for (int k = 0; k < 3; k++) {
        int idx = k * 256 + t; int vv = idx / 12; int cp = idx - vv * 12;
        float a = lds[4 * cp + 0][vv] * 128.f;
        float b = lds[4 * cp + 1][vv] * 128.f;
        float c = lds[4 * cp + 2][vv] * 128.f;
        float d = lds[4 * cp + 3][vv] * 128.f;
        uint w = (uint)__builtin_amdgcn_cvt_pk_fp8_f32(a, b, 0, false);
        w = (uint)__builtin_amdgcn_cvt_pk_fp8_f32(c, d, w, true);
        op[(v0 + vv) * 12 + cp] = w;
    }
}

// ---- main kernel: 2 rays per block (256 threads = 4 waves), 5 blocks/CU ----
// Both MLPs via MFMA 16x16x16_f16 (layouts HW-verified R13/R14). Two-pass X
// staging halves sX -> LDS 28.4 KB -> 5 blocks/CU. fp32 accum only (R9/R10).
// TR=true: gspace [3][R][R][48] fp8 x128. feat ALWAYS original [32][R][R][R] f32.
template<bool TR>
__global__ __launch_bounds__(256, 5) void lrv_main(
    const float* __restrict__ rays_d,
    const float* __restrict__ pts,
    const float* __restrict__ times,
    const float* __restrict__ deltas,
    const float* __restrict__ bg,
    const void* __restrict__ gspace_p,
    const float* __restrict__ gtime,    // [12][TT] (global; 7.2 KB L1/L2-hot)
    const float* __restrict__ feat,     // [NF][R][R][R] f32 (original)
    const float* __restrict__ W1, const float* __restrict__ b1,
    const float* __restrict__ W2, const float* __restrict__ b2,
    const float* __restrict__ Wc1, const float* __restrict__ bc1,
    const float* __restrict__ Wc2, const float* __restrict__ bc2,
    const int*  __restrict__ ridx,
    float* __restrict__ out)
{
    __shared__ __align__(16) _Float16 sW1t[64 * 48];  // [n][k]=W1[k][n], k>=35->0   6144 B
    __shared__ __align__(16) _Float16 sW2t[16 * 68];  // [o][n]=W2[n][o], stride 68  2176 B
    __shared__ __align__(16) _Float16 sWc1t[64 * 36]; // [n][k]=Wc1[k][n], stride 36 4608 B
    __shared__ __align__(16) _Float16 sWc2t[16 * 68]; // [o][n]=Wc2[n][o], pad rows  2176 B
    __shared__ __align__(16) _Float16 sX[4 * 32 * 48];// per-wave 32-row X/S region 12288 B
    __shared__ __align__(16) float4 sFeatV[8][8];     // 1024 B
    __shared__ float sb1[64], sbc1[64], sb2[16], sbc2[4];
    __shared__ int sV[4], sU[4];
    __shared__ float waveTot[4];
    __shared__ float4 rbuf[4];

    const int tid  = threadIdx.x;
    const int lane = tid & 63;
    const int wv   = tid >> 6;          // wave in block, 0..3
    const int lg   = lane >> 4;         // lane group 0..3
    const int ll   = lane & 15;
    const int myPass = lane >> 5;       // which staging pass owns my sample
    const int mrow   = lane & 31;       // my row within the 32-row region

    {
        for (int k = tid; k < 64 * 48; k += 256) {
            int n = k / 48, kk = k - n * 48;
            sW1t[k] = (_Float16)((kk < 35) ? W1[kk * 64 + n] : 0.f);
        }
        for (int k = tid; k < 16 * 68; k += 256) {
            int o = k / 68, n = k - o * 68;
            sW2t[k] = (_Float16)((n < 64) ? W2[n * 16 + o] : 0.f);
        }
        for (int k = tid; k < 64 * 36; k += 256) {
            int n = k / 36, kk = k - n * 36;
            sWc1t[k] = (_Float16)((kk < 18) ? Wc1[kk * 64 + n] : 0.f);
        }
        for (int k = tid; k < 16 * 68; k += 256) {
            int o = k / 68, n = k - o * 68;
            sWc2t[k] = (_Float16)((o < 3 && n < 64) ? Wc2[n * 3 + o] : 0.f);
        }
        if (tid < 64) { sb1[tid] = b1[tid]; sbc1[tid] = bc1[tid]; }
        if (tid < 16) sb2[tid] = b2[tid];
        if (tid < 3)  sbc2[tid] = bc2[tid];
    }
    __syncthreads();

    const int ray = blockIdx.x * 2 + (tid >> 7);
    const int i   = ray * 128 + (tid & 127);

    // ---- 1D time grid sample -> itv[12] ----
    float itv[12];
    {
        float t = times[i];
        float x = (t + 1.f) * 0.5f * (float)(TT - 1);
        x = fminf(fmaxf(x, 0.f), (float)(TT - 1));
        int ti0 = (int)floorf(x);
        ti0 = min(max(ti0, 0), TT - 2);
        float tw = x - (float)ti0;
        #pragma unroll
        for (int c = 0; c < 12; c++) {
            float v0 = gtime[c * TT + ti0];
            float v1 = gtime[c * TT + ti0 + 1];
            itv[c] = fmaf(tw, v1 - v0, v0);
        }
    }

    // ---- 3 plane bilinear samples, low-rank contraction ----
    float p0 = pts[i * 3 + 0], p1 = pts[i * 3 + 1], p2 = pts[i * 3 + 2];
    int   pbia[3], pbib[3];
    float pw[3][4];
    {
        const float pa[3] = { p0, p0, p1 };
        const float pb[3] = { p1, p2, p2 };
        #pragma unroll
        for (int c = 0; c < 3; c++) {
            float xa = fminf(fmaxf((pa[c] + 1.f) * 0.5f * (float)(RR - 1), 0.f), (float)(RR - 1));
            float xb = fminf(fmaxf((pb[c] + 1.f) * 0.5f * (float)(RR - 1), 0.f), (float)(RR - 1));
            int ia = min(max((int)floorf(xa), 0), RR - 2);
            int ib = min(max((int)floorf(xb), 0), RR - 2);
            float wa = xa - (float)ia, wb = xb - (float)ib;
            pbia[c] = ia; pbib[c] = ib;
            pw[c][0] = (1.f - wa) * (1.f - wb);
            pw[c][1] = (1.f - wa) * wb;
            pw[c][2] = wa * (1.f - wb);
            pw[c][3] = wa * wb;
        }
    }
    float S12[12];
    if constexpr (TR) {
        const uint* gs = (const uint*)gspace_p;
        uint b[3][4];
        #pragma unroll
        for (int c = 0; c < 3; c++) {
            uint b00 = ((uint)c * (RR * RR) + (uint)pbia[c] * RR + (uint)pbib[c]) * 12u;
            b[c][0] = b00;            b[c][1] = b00 + 12u;
            b[c][2] = b00 + RR * 12u; b[c][3] = b00 + RR * 12u + 12u;
        }
        #pragma unroll
        for (int cb = 0; cb < 3; cb++) {       // 16 channels per iteration
            vf2 pr[8];
            #pragma unroll
            for (int p = 0; p < 3; p++) {
                vf2 a[8];
                #pragma unroll
                for (int j = 0; j < 8; j++) { a[j][0] = 0.f; a[j][1] = 0.f; }
                #pragma unroll
                for (int corner = 0; corner < 4; corner++) {
                    u4v q = *reinterpret_cast<const u4v*>(gs + b[p][corner] + cb * 4);
                    up16p(q, pw[p][corner] * 0.0078125f, a);   // 1/128
                }
                #pragma unroll
                for (int j = 0; j < 8; j++) pr[j] = (p == 0) ? a[j] : pr[j] * a[j];
            }
            #pragma unroll
            for (int g = 0; g < 4; g++)
                S12[cb * 4 + g] = pr[2 * g][0] + pr[2 * g][1]
                                + pr[2 * g + 1][0] + pr[2 * g + 1][1];
        }
    } else {
        const float* gs = (const float*)gspace_p;
        #pragma unroll
        for (int k = 0; k < 12; k++) S12[k] = 0.f;
        #pragma unroll 4
        for (int ch = 0; ch < NCH; ch++) {
            float prod = 1.f;
            #pragma unroll
            for (int c = 0; c < 3; c++) {
                const float* g = gs + (size_t)(c * NCH + ch) * (RR * RR)
                               + pbia[c] * RR + pbib[c];
                float v = pw[c][0] * g[0] + pw[c][1] * g[1]
                        + pw[c][2] * g[RR] + pw[c][3] * g[RR + 1];
                prod *= v;
            }
            S12[ch >> 2] += prod;
        }
    }
    float cc[3];
    #pragma unroll
    for (int o = 0; o < 3; o++) {
        float a = 0.f;
        #pragma unroll
        for (int t = 0; t < 4; t++) a += S12[o * 4 + t] * itv[o * 4 + t];
        cc[o] = fminf(fmaxf(a, -1.f), 1.f);
    }

    // ---- 3D feature trilinear sample ----
    __align__(16) float in35[36];
    int   fi[3];
    float cw[8];
    {
        float fw[3];
        #pragma unroll
        for (int k = 0; k < 3; k++) {
            float xk = fminf(fmaxf((cc[k] + 1.f) * 0.5f * (float)(RR - 1), 0.f), (float)(RR - 1));
            int ik = min(max((int)floorf(xk), 0), RR - 2);
            fi[k] = ik; fw[k] = xk - (float)ik;
        }
        float w0 = fw[0], w1 = fw[1], w2 = fw[2];
        cw[0] = (1.f - w0) * (1.f - w1) * (1.f - w2);
        cw[1] = (1.f - w0) * (1.f - w1) * w2;
        cw[2] = (1.f - w0) * w1 * (1.f - w2);
        cw[3] = (1.f - w0) * w1 * w2;
        cw[4] = w0 * (1.f - w1) * (1.f - w2);
        cw[5] = w0 * (1.f - w1) * w2;
        cw[6] = w0 * w1 * (1.f - w2);
        cw[7] = w0 * w1 * w2;
    }
    // block-wide vote: do all 256 samples share one base voxel?
    {
        int packed = (fi[0] << 16) | (fi[1] << 8) | fi[2];
        int first  = __builtin_amdgcn_readfirstlane(packed);
        unsigned long long bal = __ballot(packed == first);
        if (lane == 0) { sV[wv] = first; sU[wv] = (bal == ~0ull) ? 1 : 0; }
    }
    __syncthreads();
    const bool uni = sU[0] && sU[1] && sU[2] && sU[3] &&
                     sV[0] == sV[1] && sV[1] == sV[2] && sV[2] == sV[3];
    const size_t V3 = (size_t)RR * RR * RR;
    if (uni) {
        {
            int c  = tid >> 5;           // corner 0..7  (bit2=x, bit1=y, bit0=z)
            int ch = tid & 31;
            size_t off = (((size_t)(fi[0] + ((c >> 2) & 1)) * RR
                         + (size_t)(fi[1] + ((c >> 1) & 1))) * RR
                         + (size_t)(fi[2] + (c & 1)));
            ((float*)sFeatV)[c * 32 + ch] = feat[(size_t)ch * V3 + off];
        }
        __syncthreads();
        float4* in4 = reinterpret_cast<float4*>(in35);
        #pragma unroll
        for (int chq = 0; chq < 8; chq++) {
            float4 acc = make_float4(0.f, 0.f, 0.f, 0.f);
            #pragma unroll
            for (int c = 0; c < 8; c++) {
                float4 v = sFeatV[c][chq];
                acc.x = fmaf(cw[c], v.x, acc.x);
                acc.y = fmaf(cw[c], v.y, acc.y);
                acc.z = fmaf(cw[c], v.z, acc.z);
                acc.w = fmaf(cw[c], v.w, acc.w);
            }
            in4[chq] = acc;
        }
    } else {
        size_t fb = ((size_t)fi[0] * RR + fi[1]) * RR + fi[2];
        #pragma unroll 4
        for (int ch = 0; ch < NF; ch++) {
            const float* f = feat + (size_t)ch * V3 + fb;
            in35[ch] = cw[0] * f[0]            + cw[1] * f[1]
                     + cw[2] * f[RR]           + cw[3] * f[RR + 1]
                     + cw[4] * f[RR * RR]      + cw[5] * f[RR * RR + 1]
                     + cw[6] * f[RR * RR + RR] + cw[7] * f[RR * RR + RR + 1];
        }
    }
    // ray direction (normalized)
    {
        int r = ridx[i];
        float d0 = rays_d[r * 3 + 0], d1 = rays_d[r * 3 + 1], d2 = rays_d[r * 3 + 2];
        float inv = 1.f / sqrtf(d0 * d0 + d1 * d1 + d2 * d2);
        in35[32] = d0 * inv; in35[33] = d1 * inv; in35[34] = d2 * inv;
    }

    // ---- MLP1 via MFMA, two 32-sample passes ----
    _Float16* Xw = sX + wv * (32 * 48);     // this wave's 32-row X region
    float* Srow  = (float*)Xw;              // reused as S[m][20] f32 per pass

    fv4 bb[4];
    #pragma unroll
    for (int hr = 0; hr < 4; hr++)
        bb[hr] = *(const fv4*)&sb1[hr * 16 + (lg << 2)];
    fv4 b2v = *(const fv4*)&sb2[lg << 2];

    float sacc[16];
    #pragma unroll
    for (int pass = 0; pass < 2; pass++) {
        // stage this pass's 32 X rows (48 f16: 35 inputs + zero pad)
        if (myPass == pass) {
            u4v xw[6];
            #pragma unroll
            for (int t6 = 0; t6 < 6; t6++) {
                #pragma unroll
                for (int e = 0; e < 4; e++) {
                    int q = t6 * 4 + e;
                    float a = (2 * q     < 35) ? in35[2 * q]     : 0.f;
                    float b = (2 * q + 1 < 35) ? in35[2 * q + 1] : 0.f;
                    xw[t6][e] = __builtin_bit_cast(uint, pack2(a, b));
                }
            }
            u4v* xrow = (u4v*)(Xw + mrow * 48);
            #pragma unroll
            for (int t6 = 0; t6 < 6; t6++) xrow[t6] = xw[t6];
        }
        fv4 acc1[4][2];
        #pragma unroll
        for (int hr = 0; hr < 4; hr++) { acc1[hr][0] = bb[hr]; acc1[hr][1] = bb[hr]; }
        #pragma unroll
        for (int ks = 0; ks < 3; ks++) {
            h4 a1[4], b1f[2];
            #pragma unroll
            for (int hr = 0; hr < 4; hr++)
                a1[hr] = *(const h4*)&sW1t[(hr * 16 + ll) * 48 + ks * 16 + (lg << 2)];
            #pragma unroll
            for (int s2 = 0; s2 < 2; s2++)
                b1f[s2] = *(const h4*)&Xw[(s2 * 16 + ll) * 48 + ks * 16 + (lg << 2)];
            #pragma unroll
            for (int hr = 0; hr < 4; hr++) {
                acc1[hr][0] = __builtin_amdgcn_mfma_f32_16x16x16f16(a1[hr], b1f[0], acc1[hr][0], 0, 0, 0);
                acc1[hr][1] = __builtin_amdgcn_mfma_f32_16x16x16f16(a1[hr], b1f[1], acc1[hr][1], 0, 0, 0);
            }
        }
        #pragma unroll
        for (int s2 = 0; s2 < 2; s2++) {
            fv4 acc2 = b2v;
            #pragma unroll
            for (int ks = 0; ks < 4; ks++) {
                fv4 g = acc1[ks][s2];
                h4 hb;
                #pragma unroll
                for (int e = 0; e < 4; e++) hb[e] = (_Float16)fmaxf(g[e], 0.f);
                h4 a2 = *(const h4*)&sW2t[ll * 68 + ks * 16 + (lg << 2)];
                acc2 = __builtin_amdgcn_mfma_f32_16x16x16f16(a2, hb, acc2, 0, 0, 0);
            }
            *(fv4*)&Srow[(s2 * 16 + ll) * 20 + (lg << 2)] = acc2;
        }
        // owners of this pass read their 16 outputs before next pass overwrites
        if (myPass == pass) {
            #pragma unroll
            for (int q = 0; q < 4; q++) {
                fv4 v = *(const fv4*)&Srow[mrow * 20 + q * 4];
                sacc[q * 4 + 0] = v[0]; sacc[q * 4 + 1] = v[1];
                sacc[q * 4 + 2] = v[2]; sacc[q * 4 + 3] = v[3];
            }
        }
    }
    float sigma = __expf(fminf(fmaxf(sacc[0], -15.f), 15.f));

    // ---- color MLP via MFMA, two 32-sample passes ----
    fv4 bbc[4];
    #pragma unroll
    for (int hr = 0; hr < 4; hr++)
        bbc[hr] = *(const fv4*)&sbc1[hr * 16 + (lg << 2)];
    fv4 c2bias;
    c2bias[0] = (lg == 0) ? sbc2[0] : 0.f;
    c2bias[1] = (lg == 0) ? sbc2[1] : 0.f;
    c2bias[2] = (lg == 0) ? sbc2[2] : 0.f;
    c2bias[3] = 0.f;

    float rc0 = 0.f, rc1 = 0.f, rc2 = 0.f;
    #pragma unroll
    for (int pass = 0; pass < 2; pass++) {
        if (myPass == pass) {
            // stage Xc row: 18 inputs -> cols 0..31 (k>=18 weights are 0)
            float xi[18];
            #pragma unroll
            for (int k = 0; k < 15; k++) xi[k] = sacc[k + 1];
            xi[15] = in35[32]; xi[16] = in35[33]; xi[17] = in35[34];
            uint wd[16];
            #pragma unroll
            for (int q = 0; q < 9; q++)
                wd[q] = __builtin_bit_cast(uint, pack2(xi[2 * q], (2 * q + 1 < 18) ? xi[2 * q + 1] : 0.f));
            #pragma unroll
            for (int q = 9; q < 16; q++) wd[q] = 0u;
            u4v* xrow = (u4v*)(Xw + mrow * 48);
            #pragma unroll
            for (int t4 = 0; t4 < 4; t4++) {
                u4v v; v[0] = wd[t4 * 4 + 0]; v[1] = wd[t4 * 4 + 1];
                       v[2] = wd[t4 * 4 + 2]; v[3] = wd[t4 * 4 + 3];
                xrow[t4] = v;
            }
        }
        #pragma unroll
        for (int scl = 0; scl < 2; scl++) {
            fv4 acc1c[4];
            #pragma unroll
            for (int hr = 0; hr < 4; hr++) acc1c[hr] = bbc[hr];
            #pragma unroll
            for (int ks = 0; ks < 2; ks++) {
                h4 bfrag = *(const h4*)&Xw[(scl * 16 + ll) * 48 + ks * 16 + (lg << 2)];
                #pragma unroll
                for (int hr = 0; hr < 4; hr++) {
                    h4 a = *(const h4*)&sWc1t[(hr * 16 + ll) * 36 + ks * 16 + (lg << 2)];
                    acc1c[hr] = __builtin_amdgcn_mfma_f32_16x16x16f16(a, bfrag, acc1c[hr], 0, 0, 0);
                }
            }
            fv4 acc2c = c2bias;
            #pragma unroll
            for (int ks = 0; ks < 4; ks++) {
                fv4 g = acc1c[ks];
                h4 hb;
                #pragma unroll
                for (int e = 0; e < 4; e++) hb[e] = (_Float16)fmaxf(g[e], 0.f);
                h4 a2 = *(const h4*)&sWc2t[ll * 68 + ks * 16 + (lg << 2)];
                acc2c = __builtin_amdgcn_mfma_f32_16x16x16f16(a2, hb, acc2c, 0, 0, 0);
            }
            // rgb rows 0..2 live in lg==0 lanes, col=ll
            float t0 = __shfl(acc2c[0], ll, 64);
            float t1 = __shfl(acc2c[1], ll, 64);
            float t2 = __shfl(acc2c[2], ll, 64);
            if (lg == pass * 2 + scl) { rc0 = t0; rc1 = t1; rc2 = t2; }
        }
    }
    float r_ = 1.f / (1.f + __expf(-rc0));
    float g_ = 1.f / (1.f + __expf(-rc1));
    float b_ = 1.f / (1.f + __expf(-rc2));

    // ---- per-ray compositing: exclusive scan of tau over 128 samples ----
    float tau = sigma * deltas[i];
    float v = tau;
    #pragma unroll
    for (int off = 1; off < 64; off <<= 1) {
        float u = __shfl_up(v, off, 64);
        if (lane >= off) v += u;
    }
    if (lane == 63) waveTot[wv] = v;
    float excl = v - tau;
    __syncthreads();
    if (wv & 1) excl += waveTot[wv & 2];

    float Tr = __expf(-excl);
    float w  = Tr * (1.f - __expf(-tau));

    float ax = w * r_, ay = w * g_, az = w * b_, aw = w;
    #pragma unroll
    for (int off = 32; off; off >>= 1) {
        ax += __shfl_down(ax, off, 64);
        ay += __shfl_down(ay, off, 64);
        az += __shfl_down(az, off, 64);
        aw += __shfl_down(aw, off, 64);
    }
    if (lane == 0) rbuf[wv] = make_float4(ax, ay, az, aw);
    __syncthreads();
    if (lane == 0 && (wv & 1) == 0) {
        float cx = rbuf[wv].x + rbuf[wv + 1].x;
        float cy = rbuf[wv].y + rbuf[wv + 1].y;
        float cz = rbuf[wv].z + rbuf[wv + 1].z;
        float alpha = rbuf[wv].w + rbuf[wv + 1].w;
        out[ray * 3 + 0] = cx + (1.f - alpha) * bg[ray * 3 + 0];
        out[ray * 3 + 1] = cy + (1.f - alpha) * bg[ray * 3 + 1];
        out[ray * 3 + 2] = cz + (1.f - alpha) * bg[ray * 3 + 2];
    }
}

extern "C" void kernel_launch(void* const* d_in, const int* in_sizes, int n_in,
                              void* d_out, int out_size, void* d_ws, size_t ws_size,
                              hipStream_t stream) {
    const float* rays_d = (const float*)d_in[0];
    const float* pts    = (const float*)d_in[1];
    const float* times  = (const float*)d_in[2];
    const float* deltas = (const float*)d_in[3];
    const float* bg     = (const float*)d_in[4];
    const float* gspace = (const float*)d_in[5];
    const float* gtime  = (const float*)d_in[6];
    const float* feat   = (const float*)d_in[7];
    const float* W1  = (const float*)d_in[8];
    const float* b1  = (const float*)d_in[9];
    const float* W2  = (const float*)d_in[10];
    const float* b2  = (const float*)d_in[11];
    const float* Wc1 = (const float*)d_in[12];
    const float* bc1 = (const float*)d_in[13];
    const float* Wc2 = (const float*)d_in[14];
    const float* bc2 = (const float*)d_in[15];
    const int*   ridx = (const int*)d_in[16];

    const int n_rays = in_sizes[0] / 3;   // 4096

    const size_t GSP_8B = (size_t)3 * RR * RR * NCH;   // 2.35 MB (fp8)

    if (ws_size >= GSP_8B) {
        uint* gsp_t = (uint*)d_ws;
        tgsp_8<<<dim3(3 * 256), dim3(256), 0, stream>>>(gspace, gsp_t);
        lrv_main<true><<<dim3(n_rays / 2), dim3(256), 0, stream>>>(
            rays_d, pts, times, deltas, bg, (const void*)gsp_t, gtime, feat,
            W1, b1, W2, b2, Wc1, bc1, Wc2, bc2, ridx, (float*)d_out);
    } else {
        lrv_main<false><<<dim3(n_rays / 2), dim3(256), 0, stream>>>(
            rays_d, pts, times, deltas, bg, (const void*)gspace, gtime, feat,
            W1, b1, W2, b2, Wc1, bc1, Wc2, bc2, ridx, (float*)d_out);
    }
}

// Round 16
// 114.950 us; speedup vs baseline: 1.2882x; 1.2882x over previous
//
#include <hip/hip_runtime.h>
#include <hip/hip_fp16.h>
#include <math.h>

#define RR 128          // spatial resolution (grid_space + features)
#define TT 150          // time resolution
#define NCH 48          // RANK*OUT_DIM*TIME_RANK
#define NF 32           // feature channels

typedef float vf2 __attribute__((ext_vector_type(2)));
typedef unsigned int u4v __attribute__((ext_vector_type(4)));
typedef _Float16 h2 __attribute__((ext_vector_type(2)));
typedef _Float16 h4 __attribute__((ext_vector_type(4)));
typedef float fv4 __attribute__((ext_vector_type(4)));

__device__ __forceinline__ h2 pack2(float a, float b) {
    h2 r; r[0] = (_Float16)a; r[1] = (_Float16)b; return r;
}
// fp8 e4m3 unpack with packed-f32 accumulate (v_pk_fma_f32)
__device__ __forceinline__ void up4p(uint u, vf2 s, vf2* a) {
    a[0] += __builtin_amdgcn_cvt_pk_f32_fp8(u, false) * s;
    a[1] += __builtin_amdgcn_cvt_pk_f32_fp8(u, true) * s;
}
__device__ __forceinline__ void up16p(u4v q, float sf, vf2* a) {
    vf2 s; s[0] = sf; s[1] = sf;
    up4p(q[0], s, a + 0); up4p(q[1], s, a + 2);
    up4p(q[2], s, a + 4); up4p(q[3], s, a + 6);
}

// ---- transpose+cast grid_space [3][48][16384] f32 -> [3][16384][48] fp8 (x128) ----
__global__ __launch_bounds__(256) void tgsp_8(const float* __restrict__ in,
                                              uint* __restrict__ out) { // 4 fp8/word
    __shared__ float lds[48][65];
    const int t = threadIdx.x;
    const int p = blockIdx.x >> 8;          // plane
    const int tile = blockIdx.x & 255;
    const size_t V = (size_t)RR * RR;       // 16384
    const size_t v0 = (size_t)tile * 64;
    const float* ip = in + (size_t)p * NCH * V;
    uint* op = out + (size_t)p * V * 12;    // 12 words per position
    #pragma unroll
    for (int k = 0; k < 12; k++) {
        int idx = k * 256 + t; int c = idx >> 6; int vv = idx & 63;
        lds[c][vv] = ip[(size_t)c * V + v0 + vv];
    }
    __syncthreads();
    #pragma unroll
    for (int k = 0; k < 3; k++) {
        int idx = k * 256 + t; int vv = idx / 12; int cp = idx - vv * 12;
        float a = lds[4 * cp + 0][vv] * 128.f;
        float b = lds[4 * cp + 1][vv] * 128.f;
        float c = lds[4 * cp + 2][vv] * 128.f;
        float d = lds[4 * cp + 3][vv] * 128.f;
        uint w = (uint)__builtin_amdgcn_cvt_pk_fp8_f32(a, b, 0, false);
        w = (uint)__builtin_amdgcn_cvt_pk_fp8_f32(c, d, w, true);
        op[(v0 + vv) * 12 + cp] = w;
    }
}

// ---- main kernel: 2 rays per block (256 threads = 4 waves), 4 blocks/CU ----
// R14 config (best: 115.6 us). Both MLPs via MFMA 16x16x16_f16 (layouts
// HW-verified R13/R14). fp32 accum only (fp16-accum spills: R9/R10).
// Two-pass/5-block variant regressed (R15: 4.65M LDS bank conflicts).
// Occupancy raises never helped (R5/R11/R15) — kernel is serial-chain bound.
// TR=true: gspace [3][R][R][48] fp8 x128. feat ALWAYS original [32][R][R][R] f32.
template<bool TR>
__global__ __launch_bounds__(256, 4) void lrv_main(
    const float* __restrict__ rays_d,
    const float* __restrict__ pts,
    const float* __restrict__ times,
    const float* __restrict__ deltas,
    const float* __restrict__ bg,
    const void* __restrict__ gspace_p,
    const float* __restrict__ gtime,    // [12][TT] (global; 7.2 KB L1/L2-hot)
    const float* __restrict__ feat,     // [NF][R][R][R] f32 (original)
    const float* __restrict__ W1, const float* __restrict__ b1,
    const float* __restrict__ W2, const float* __restrict__ b2,
    const float* __restrict__ Wc1, const float* __restrict__ bc1,
    const float* __restrict__ Wc2, const float* __restrict__ bc2,
    const int*  __restrict__ ridx,
    float* __restrict__ out)
{
    __shared__ __align__(16) _Float16 sW1t[64 * 48];  // [n][k]=W1[k][n], k>=35->0   6144 B
    __shared__ __align__(16) _Float16 sW2t[16 * 68];  // [o][n]=W2[n][o], stride 68  2176 B
    __shared__ __align__(16) _Float16 sWc1t[64 * 36]; // [n][k]=Wc1[k][n], stride 36 4608 B
    __shared__ __align__(16) _Float16 sWc2t[16 * 68]; // [o][n]=Wc2[n][o], pad rows  2176 B
    __shared__ __align__(16) _Float16 sX[4 * 64 * 48];// per-wave X/S/Xc region     24576 B
    __shared__ float sb1[64], sbc1[64], sb2[16], sbc2[4];
    __shared__ int sV[4], sU[4];
    __shared__ float waveTot[4];
    __shared__ float4 rbuf[4];
    // sFeatV overlaid on sX (consumed before X staging; barrier-separated)
    float4 (*sFeatV)[8] = reinterpret_cast<float4(*)[8]>(sX);

    const int tid  = threadIdx.x;
    const int lane = tid & 63;
    const int wv   = tid >> 6;          // wave in block, 0..3
    const int lg   = lane >> 4;         // lane group 0..3
    const int ll   = lane & 15;

    {
        for (int k = tid; k < 64 * 48; k += 256) {
            int n = k / 48, kk = k - n * 48;
            sW1t[k] = (_Float16)((kk < 35) ? W1[kk * 64 + n] : 0.f);
        }
        for (int k = tid; k < 16 * 68; k += 256) {
            int o = k / 68, n = k - o * 68;
            sW2t[k] = (_Float16)((n < 64) ? W2[n * 16 + o] : 0.f);
        }
        for (int k = tid; k < 64 * 36; k += 256) {
            int n = k / 36, kk = k - n * 36;
            sWc1t[k] = (_Float16)((kk < 18) ? Wc1[kk * 64 + n] : 0.f);
        }
        for (int k = tid; k < 16 * 68; k += 256) {
            int o = k / 68, n = k - o * 68;
            sWc2t[k] = (_Float16)((o < 3 && n < 64) ? Wc2[n * 3 + o] : 0.f);
        }
        if (tid < 64) { sb1[tid] = b1[tid]; sbc1[tid] = bc1[tid]; }
        if (tid < 16) sb2[tid] = b2[tid];
        if (tid < 3)  sbc2[tid] = bc2[tid];
    }
    __syncthreads();

    const int ray = blockIdx.x * 2 + (tid >> 7);
    const int i   = ray * 128 + (tid & 127);

    // ---- 1D time grid sample -> itv[12] ----
    float itv[12];
    {
        float t = times[i];
        float x = (t + 1.f) * 0.5f * (float)(TT - 1);
        x = fminf(fmaxf(x, 0.f), (float)(TT - 1));
        int ti0 = (int)floorf(x);
        ti0 = min(max(ti0, 0), TT - 2);
        float tw = x - (float)ti0;
        #pragma unroll
        for (int c = 0; c < 12; c++) {
            float v0 = gtime[c * TT + ti0];
            float v1 = gtime[c * TT + ti0 + 1];
            itv[c] = fmaf(tw, v1 - v0, v0);
        }
    }

    // ---- 3 plane bilinear samples, low-rank contraction ----
    float p0 = pts[i * 3 + 0], p1 = pts[i * 3 + 1], p2 = pts[i * 3 + 2];
    int   pbia[3], pbib[3];
    float pw[3][4];
    {
        const float pa[3] = { p0, p0, p1 };
        const float pb[3] = { p1, p2, p2 };
        #pragma unroll
        for (int c = 0; c < 3; c++) {
            float xa = fminf(fmaxf((pa[c] + 1.f) * 0.5f * (float)(RR - 1), 0.f), (float)(RR - 1));
            float xb = fminf(fmaxf((pb[c] + 1.f) * 0.5f * (float)(RR - 1), 0.f), (float)(RR - 1));
            int ia = min(max((int)floorf(xa), 0), RR - 2);
            int ib = min(max((int)floorf(xb), 0), RR - 2);
            float wa = xa - (float)ia, wb = xb - (float)ib;
            pbia[c] = ia; pbib[c] = ib;
            pw[c][0] = (1.f - wa) * (1.f - wb);
            pw[c][1] = (1.f - wa) * wb;
            pw[c][2] = wa * (1.f - wb);
            pw[c][3] = wa * wb;
        }
    }
    float S12[12];
    if constexpr (TR) {
        const uint* gs = (const uint*)gspace_p;
        uint b[3][4];
        #pragma unroll
        for (int c = 0; c < 3; c++) {
            uint b00 = ((uint)c * (RR * RR) + (uint)pbia[c] * RR + (uint)pbib[c]) * 12u;
            b[c][0] = b00;            b[c][1] = b00 + 12u;
            b[c][2] = b00 + RR * 12u; b[c][3] = b00 + RR * 12u + 12u;
        }
        #pragma unroll
        for (int cb = 0; cb < 3; cb++) {       // 16 channels per iteration
            vf2 pr[8];
            #pragma unroll
            for (int p = 0; p < 3; p++) {
                vf2 a[8];
                #pragma unroll
                for (int j = 0; j < 8; j++) { a[j][0] = 0.f; a[j][1] = 0.f; }
                #pragma unroll
                for (int corner = 0; corner < 4; corner++) {
                    u4v q = *reinterpret_cast<const u4v*>(gs + b[p][corner] + cb * 4);
                    up16p(q, pw[p][corner] * 0.0078125f, a);   // 1/128
                }
                #pragma unroll
                for (int j = 0; j < 8; j++) pr[j] = (p == 0) ? a[j] : pr[j] * a[j];
            }
            #pragma unroll
            for (int g = 0; g < 4; g++)
                S12[cb * 4 + g] = pr[2 * g][0] + pr[2 * g][1]
                                + pr[2 * g + 1][0] + pr[2 * g + 1][1];
        }
    } else {
        const float* gs = (const float*)gspace_p;
        #pragma unroll
        for (int k = 0; k < 12; k++) S12[k] = 0.f;
        #pragma unroll 4
        for (int ch = 0; ch < NCH; ch++) {
            float prod = 1.f;
            #pragma unroll
            for (int c = 0; c < 3; c++) {
                const float* g = gs + (size_t)(c * NCH + ch) * (RR * RR)
                               + pbia[c] * RR + pbib[c];
                float v = pw[c][0] * g[0] + pw[c][1] * g[1]
                        + pw[c][2] * g[RR] + pw[c][3] * g[RR + 1];
                prod *= v;
            }
            S12[ch >> 2] += prod;
        }
    }
    float cc[3];
    #pragma unroll
    for (int o = 0; o < 3; o++) {
        float a = 0.f;
        #pragma unroll
        for (int t = 0; t < 4; t++) a += S12[o * 4 + t] * itv[o * 4 + t];
        cc[o] = fminf(fmaxf(a, -1.f), 1.f);
    }

    // ---- 3D feature trilinear sample ----
    __align__(16) float in35[36];
    int   fi[3];
    float cw[8];
    {
        float fw[3];
        #pragma unroll
        for (int k = 0; k < 3; k++) {
            float xk = fminf(fmaxf((cc[k] + 1.f) * 0.5f * (float)(RR - 1), 0.f), (float)(RR - 1));
            int ik = min(max((int)floorf(xk), 0), RR - 2);
            fi[k] = ik; fw[k] = xk - (float)ik;
        }
        float w0 = fw[0], w1 = fw[1], w2 = fw[2];
        cw[0] = (1.f - w0) * (1.f - w1) * (1.f - w2);
        cw[1] = (1.f - w0) * (1.f - w1) * w2;
        cw[2] = (1.f - w0) * w1 * (1.f - w2);
        cw[3] = (1.f - w0) * w1 * w2;
        cw[4] = w0 * (1.f - w1) * (1.f - w2);
        cw[5] = w0 * (1.f - w1) * w2;
        cw[6] = w0 * w1 * (1.f - w2);
        cw[7] = w0 * w1 * w2;
    }
    // block-wide vote: do all 256 samples share one base voxel?
    {
        int packed = (fi[0] << 16) | (fi[1] << 8) | fi[2];
        int first  = __builtin_amdgcn_readfirstlane(packed);
        unsigned long long bal = __ballot(packed == first);
        if (lane == 0) { sV[wv] = first; sU[wv] = (bal == ~0ull) ? 1 : 0; }
    }
    __syncthreads();
    const bool uni = sU[0] && sU[1] && sU[2] && sU[3] &&
                     sV[0] == sV[1] && sV[1] == sV[2] && sV[2] == sV[3];
    const size_t V3 = (size_t)RR * RR * RR;
    if (uni) {
        {
            int c  = tid >> 5;           // corner 0..7  (bit2=x, bit1=y, bit0=z)
            int ch = tid & 31;
            size_t off = (((size_t)(fi[0] + ((c >> 2) & 1)) * RR
                         + (size_t)(fi[1] + ((c >> 1) & 1))) * RR
                         + (size_t)(fi[2] + (c & 1)));
            ((float*)sFeatV)[c * 32 + ch] = feat[(size_t)ch * V3 + off];
        }
        __syncthreads();
        float4* in4 = reinterpret_cast<float4*>(in35);
        #pragma unroll
        for (int chq = 0; chq < 8; chq++) {
            float4 acc = make_float4(0.f, 0.f, 0.f, 0.f);
            #pragma unroll
            for (int c = 0; c < 8; c++) {
                float4 v = sFeatV[c][chq];
                acc.x = fmaf(cw[c], v.x, acc.x);
                acc.y = fmaf(cw[c], v.y, acc.y);
                acc.z = fmaf(cw[c], v.z, acc.z);
                acc.w = fmaf(cw[c], v.w, acc.w);
            }
            in4[chq] = acc;
        }
    } else {
        size_t fb = ((size_t)fi[0] * RR + fi[1]) * RR + fi[2];
        #pragma unroll 4
        for (int ch = 0; ch < NF; ch++) {
            const float* f = feat + (size_t)ch * V3 + fb;
            in35[ch] = cw[0] * f[0]            + cw[1] * f[1]
                     + cw[2] * f[RR]           + cw[3] * f[RR + 1]
                     + cw[4] * f[RR * RR]      + cw[5] * f[RR * RR + 1]
                     + cw[6] * f[RR * RR + RR] + cw[7] * f[RR * RR + RR + 1];
        }
    }
    // ray direction (normalized)
    {
        int r = ridx[i];
        float d0 = rays_d[r * 3 + 0], d1 = rays_d[r * 3 + 1], d2 = rays_d[r * 3 + 2];
        float inv = 1.f / sqrtf(d0 * d0 + d1 * d1 + d2 * d2);
        in35[32] = d0 * inv; in35[33] = d1 * inv; in35[34] = d2 * inv;
    }
    // barrier: sFeatV (overlaid on sX) fully consumed before X staging
    __syncthreads();

    // ---- MLP1 via MFMA: Ht = relu(W1t·Xt + b1); S = W2t·Ht + b2 ----
    _Float16* Xw = sX + wv * (64 * 48);     // this wave's X[m][k] (m=lane)
    float* Srow  = (float*)Xw;              // reused as S[m][20] f32 (writes follow all X reads)

    // stage my X row: 48 f16 (35 inputs + zero pad) = 6 x 16B
    {
        u4v xw[6];
        #pragma unroll
        for (int t6 = 0; t6 < 6; t6++) {
            #pragma unroll
            for (int e = 0; e < 4; e++) {
                int q = t6 * 4 + e;                 // h2-word index 0..23
                float a = (2 * q     < 35) ? in35[2 * q]     : 0.f;
                float b = (2 * q + 1 < 35) ? in35[2 * q + 1] : 0.f;
                xw[t6][e] = __builtin_bit_cast(uint, pack2(a, b));
            }
        }
        u4v* xrow = (u4v*)(Xw + lane * 48);
        #pragma unroll
        for (int t6 = 0; t6 < 6; t6++) xrow[t6] = xw[t6];
    }

    // biases as C-operands
    fv4 bb[4];
    #pragma unroll
    for (int hr = 0; hr < 4; hr++)
        bb[hr] = *(const fv4*)&sb1[hr * 16 + (lg << 2)];
    fv4 b2v = *(const fv4*)&sb2[lg << 2];

    #pragma unroll
    for (int half = 0; half < 2; half++) {
        fv4 acc1[4][2];
        #pragma unroll
        for (int hr = 0; hr < 4; hr++) {
            acc1[hr][0] = bb[hr];
            acc1[hr][1] = bb[hr];
        }
        #pragma unroll
        for (int ks = 0; ks < 3; ks++) {
            h4 a1[4], b1f[2];
            #pragma unroll
            for (int hr = 0; hr < 4; hr++)
                a1[hr] = *(const h4*)&sW1t[(hr * 16 + ll) * 48 + ks * 16 + (lg << 2)];
            #pragma unroll
            for (int s2 = 0; s2 < 2; s2++) {
                int sc = half * 2 + s2;
                b1f[s2] = *(const h4*)&Xw[(sc * 16 + ll) * 48 + ks * 16 + (lg << 2)];
            }
            #pragma unroll
            for (int hr = 0; hr < 4; hr++) {
                acc1[hr][0] = __builtin_amdgcn_mfma_f32_16x16x16f16(a1[hr], b1f[0], acc1[hr][0], 0, 0, 0);
                acc1[hr][1] = __builtin_amdgcn_mfma_f32_16x16x16f16(a1[hr], b1f[1], acc1[hr][1], 0, 0, 0);
            }
        }
        // relu + cvt -> L2 B-frags (D-layout == B-layout), L2 MFMA
        #pragma unroll
        for (int s2 = 0; s2 < 2; s2++) {
            fv4 acc2 = b2v;
            #pragma unroll
            for (int ks = 0; ks < 4; ks++) {
                fv4 g = acc1[ks][s2];
                h4 hb;
                #pragma unroll
                for (int e = 0; e < 4; e++) hb[e] = (_Float16)fmaxf(g[e], 0.f);
                h4 a2 = *(const h4*)&sW2t[ll * 68 + ks * 16 + (lg << 2)];
                acc2 = __builtin_amdgcn_mfma_f32_16x16x16f16(a2, hb, acc2, 0, 0, 0);
            }
            int sc = half * 2 + s2;
            *(fv4*)&Srow[(sc * 16 + ll) * 20 + (lg << 2)] = acc2;
        }
    }

    // read my sample's 16 outputs
    float sacc[16];
    #pragma unroll
    for (int q = 0; q < 4; q++) {
        fv4 v = *(const fv4*)&Srow[lane * 20 + q * 4];
        sacc[q * 4 + 0] = v[0]; sacc[q * 4 + 1] = v[1];
        sacc[q * 4 + 2] = v[2]; sacc[q * 4 + 3] = v[3];
    }
    float sigma = __expf(fminf(fmaxf(sacc[0], -15.f), 15.f));

    // ---- color MLP via MFMA: Hc^T = relu(Wc1t·Xc^T + bc1); rgb = Wc2t·Hc^T + bc2 ----
    // restage Xc into this wave's X region (all S reads above precede writes; wave-lockstep)
    {
        float xi[18];
        #pragma unroll
        for (int k = 0; k < 15; k++) xi[k] = sacc[k + 1];
        xi[15] = in35[32]; xi[16] = in35[33]; xi[17] = in35[34];
        uint wd[16];
        #pragma unroll
        for (int q = 0; q < 9; q++)
            wd[q] = __builtin_bit_cast(uint, pack2(xi[2 * q], (2 * q + 1 < 18) ? xi[2 * q + 1] : 0.f));
        #pragma unroll
        for (int q = 9; q < 16; q++) wd[q] = 0u;
        u4v* xrow = (u4v*)(Xw + lane * 48);
        #pragma unroll
        for (int t4 = 0; t4 < 4; t4++) {
            u4v v; v[0] = wd[t4 * 4 + 0]; v[1] = wd[t4 * 4 + 1];
                   v[2] = wd[t4 * 4 + 2]; v[3] = wd[t4 * 4 + 3];
            xrow[t4] = v;
        }
    }
    fv4 bbc[4];
    #pragma unroll
    for (int hr = 0; hr < 4; hr++)
        bbc[hr] = *(const fv4*)&sbc1[hr * 16 + (lg << 2)];
    fv4 c2bias;
    c2bias[0] = (lg == 0) ? sbc2[0] : 0.f;
    c2bias[1] = (lg == 0) ? sbc2[1] : 0.f;
    c2bias[2] = (lg == 0) ? sbc2[2] : 0.f;
    c2bias[3] = 0.f;

    float rc0 = 0.f, rc1 = 0.f, rc2 = 0.f;
    #pragma unroll
    for (int sc = 0; sc < 4; sc++) {
        fv4 acc1c[4];
        #pragma unroll
        for (int hr = 0; hr < 4; hr++) acc1c[hr] = bbc[hr];
        #pragma unroll
        for (int ks = 0; ks < 2; ks++) {
            h4 bfrag = *(const h4*)&Xw[(sc * 16 + ll) * 48 + ks * 16 + (lg << 2)];
            #pragma unroll
            for (int hr = 0; hr < 4; hr++) {
                h4 a = *(const h4*)&sWc1t[(hr * 16 + ll) * 36 + ks * 16 + (lg << 2)];
                acc1c[hr] = __builtin_amdgcn_mfma_f32_16x16x16f16(a, bfrag, acc1c[hr], 0, 0, 0);
            }
        }
        fv4 acc2c = c2bias;
        #pragma unroll
        for (int ks = 0; ks < 4; ks++) {
            fv4 g = acc1c[ks];
            h4 hb;
            #pragma unroll
            for (int e = 0; e < 4; e++) hb[e] = (_Float16)fmaxf(g[e], 0.f);
            h4 a2 = *(const h4*)&sWc2t[ll * 68 + ks * 16 + (lg << 2)];
            acc2c = __builtin_amdgcn_mfma_f32_16x16x16f16(a2, hb, acc2c, 0, 0, 0);
        }
        // rgb rows 0..2 live in lg==0 lanes, col=ll; broadcast to the 16-sample group
        float t0 = __shfl(acc2c[0], ll, 64);
        float t1 = __shfl(acc2c[1], ll, 64);
        float t2 = __shfl(acc2c[2], ll, 64);
        if (lg == sc) { rc0 = t0; rc1 = t1; rc2 = t2; }
    }
    float r_ = 1.f / (1.f + __expf(-rc0));
    float g_ = 1.f / (1.f + __expf(-rc1));
    float b_ = 1.f / (1.f + __expf(-rc2));

    // ---- per-ray compositing: exclusive scan of tau over 128 samples ----
    float tau = sigma * deltas[i];
    float v = tau;
    #pragma unroll
    for (int off = 1; off < 64; off <<= 1) {
        float u = __shfl_up(v, off, 64);
        if (lane >= off) v += u;
    }
    if (lane == 63) waveTot[wv] = v;
    float excl = v - tau;
    __syncthreads();
    if (wv & 1) excl += waveTot[wv & 2];

    float Tr = __expf(-excl);
    float w  = Tr * (1.f - __expf(-tau));

    float ax = w * r_, ay = w * g_, az = w * b_, aw = w;
    #pragma unroll
    for (int off = 32; off; off >>= 1) {
        ax += __shfl_down(ax, off, 64);
        ay += __shfl_down(ay, off, 64);
        az += __shfl_down(az, off, 64);
        aw += __shfl_down(aw, off, 64);
    }
    if (lane == 0) rbuf[wv] = make_float4(ax, ay, az, aw);
    __syncthreads();
    if (lane == 0 && (wv & 1) == 0) {
        float cx = rbuf[wv].x + rbuf[wv + 1].x;
        float cy = rbuf[wv].y + rbuf[wv + 1].y;
        float cz = rbuf[wv].z + rbuf[wv + 1].z;
        float alpha = rbuf[wv].w + rbuf[wv + 1].w;
        out[ray * 3 + 0] = cx + (1.f - alpha) * bg[ray * 3 + 0];
        out[ray * 3 + 1] = cy + (1.f - alpha) * bg[ray * 3 + 1];
        out[ray * 3 + 2] = cz + (1.f - alpha) * bg[ray * 3 + 2];
    }
}

extern "C" void kernel_launch(void* const* d_in, const int* in_sizes, int n_in,
                              void* d_out, int out_size, void* d_ws, size_t ws_size,
                              hipStream_t stream) {
    const float* rays_d = (const float*)d_in[0];
    const float* pts    = (const float*)d_in[1];
    const float* times  = (const float*)d_in[2];
    const float* deltas = (const float*)d_in[3];
    const float* bg     = (const float*)d_in[4];
    const float* gspace = (const float*)d_in[5];
    const float* gtime  = (const float*)d_in[6];
    const float* feat   = (const float*)d_in[7];
    const float* W1  = (const float*)d_in[8];
    const float* b1  = (const float*)d_in[9];
    const float* W2  = (const float*)d_in[10];
    const float* b2  = (const float*)d_in[11];
    const float* Wc1 = (const float*)d_in[12];
    const float* bc1 = (const float*)d_in[13];
    const float* Wc2 = (const float*)d_in[14];
    const float* bc2 = (const float*)d_in[15];
    const int*   ridx = (const int*)d_in[16];

    const int n_rays = in_sizes[0] / 3;   // 4096

    const size_t GSP_8B = (size_t)3 * RR * RR * NCH;   // 2.35 MB (fp8)

    if (ws_size >= GSP_8B) {
        uint* gsp_t = (uint*)d_ws;
        tgsp_8<<<dim3(3 * 256), dim3(256), 0, stream>>>(gspace, gsp_t);
        lrv_main<true><<<dim3(n_rays / 2), dim3(256), 0, stream>>>(
            rays_d, pts, times, deltas, bg, (const void*)gsp_t, gtime, feat,
            W1, b1, W2, b2, Wc1, bc1, Wc2, bc2, ridx, (float*)d_out);
    } else {
        lrv_main<false><<<dim3(n_rays / 2), dim3(256), 0, stream>>>(
            rays_d, pts, times, deltas, bg, (const void*)gspace, gtime, feat,
            W1, b1, W2, b2, Wc1, bc1, Wc2, bc2, ridx, (float*)d_out);
    }
}